// Round 4
// baseline (101.225 us; speedup 1.0000x reference)
//
#include <hip/hip_runtime.h>

#define HW    12544   // 112*112
#define HW4   3136    // HW/4
#define NCH   64      // channels
#define NB    64      // batch
#define EPSF  1e-5f

typedef float fvec4 __attribute__((ext_vector_type(4)));

// ws layout (floats): [0,4096)     s_part[b*64+c]
//                     [4096,8192)  ss_part[b*64+c]
// (fully overwritten every call -> no zeroing, no atomics)
//
// Channel-split pipeline: statsA(c<32) -> normA -> statsB(c>=32) -> normB.
// Each phase's L3 footprint stays <= ~206 MB < 256 MB Infinity Cache, so the
// norm pass re-reads x from L3 instead of HBM.

__global__ __launch_bounds__(256) void cn_stats_half(const float* __restrict__ x,
                                                     float* __restrict__ ws,
                                                     int c0) {
    int c = (blockIdx.x & 31) + c0;
    int b = blockIdx.x >> 5;
    int p = b * NCH + c;
    const fvec4* xp = (const fvec4*)(x + (size_t)p * HW);
    float s = 0.0f, ss = 0.0f;
    for (int i = threadIdx.x; i < HW4; i += 256) {
        fvec4 v = xp[i];
        s  += v.x + v.y + v.z + v.w;
        ss += v.x * v.x + v.y * v.y + v.z * v.z + v.w * v.w;
    }
    #pragma unroll
    for (int off = 32; off > 0; off >>= 1) {
        s  += __shfl_down(s, off, 64);
        ss += __shfl_down(ss, off, 64);
    }
    __shared__ float sh[8];
    int lane = threadIdx.x & 63;
    int wave = threadIdx.x >> 6;
    if (lane == 0) { sh[wave] = s; sh[4 + wave] = ss; }
    __syncthreads();
    if (threadIdx.x == 0) {
        ws[p]        = sh[0] + sh[1] + sh[2] + sh[3];
        ws[4096 + p] = sh[4] + sh[5] + sh[6] + sh[7];
    }
}

__global__ __launch_bounds__(256) void cn_norm_half(const float* __restrict__ x,
                                                    const int* __restrict__ labels,
                                                    const float* __restrict__ rmean,
                                                    const float* __restrict__ rvar,
                                                    const float* __restrict__ wgt,
                                                    const float* __restrict__ bia,
                                                    const float* __restrict__ ws,
                                                    float* __restrict__ out,
                                                    int c0) {
    int c = (blockIdx.x & 31) + c0;
    int b = blockIdx.x >> 5;
    int p = b * NCH + c;
    __shared__ float sh_scale, sh_shift;
    if (threadIdx.x < 64) {
        int t = threadIdx.x;
        int g  = labels[b];         // this sample's cluster
        int lb = labels[t];         // lane t inspects sample t
        bool m = (lb == g);
        float s   = m ? ws[t * NCH + c]        : 0.0f;
        float ss  = m ? ws[4096 + t * NCH + c] : 0.0f;
        float cnt = m ? 1.0f : 0.0f;
        #pragma unroll
        for (int off = 32; off > 0; off >>= 1) {
            s   += __shfl_down(s,   off, 64);
            ss  += __shfl_down(ss,  off, 64);
            cnt += __shfl_down(cnt, off, 64);
        }
        if (t == 0) {
            float N    = cnt * (float)HW;
            float mean = s / fmaxf(N, 1.0f);
            float var  = (ss - N * mean * mean) / fmaxf(N - 1.0f, 1.0f);
            float mu   = 0.2f * mean + 0.8f * rmean[c];
            float vb   = 0.2f * var  + 0.8f * rvar[c];
            float scale = rsqrtf(vb + EPSF) * wgt[c];
            sh_scale = scale;
            sh_shift = bia[c] - mu * scale;
        }
    }
    __syncthreads();
    float scale = sh_scale;
    float shift = sh_shift;
    const fvec4* xp = (const fvec4*)(x + (size_t)p * HW);
    fvec4*       op = (fvec4*)(out + (size_t)p * HW);
    for (int i = threadIdx.x; i < HW4; i += 256) {
        fvec4 v = __builtin_nontemporal_load(&xp[i]);
        fvec4 o;
        o.x = v.x * scale + shift;
        o.y = v.y * scale + shift;
        o.z = v.z * scale + shift;
        o.w = v.w * scale + shift;
        __builtin_nontemporal_store(o, &op[i]);
    }
}

extern "C" void kernel_launch(void* const* d_in, const int* in_sizes, int n_in,
                              void* d_out, int out_size, void* d_ws, size_t ws_size,
                              hipStream_t stream) {
    const float* x      = (const float*)d_in[0];
    const float* rmean  = (const float*)d_in[1];
    const float* rvar   = (const float*)d_in[2];
    const float* wgt    = (const float*)d_in[3];
    const float* bia    = (const float*)d_in[4];
    const int*   labels = (const int*)d_in[5];
    float* out = (float*)d_out;
    float* ws  = (float*)d_ws;

    const int half = NB * (NCH / 2); // 2048 blocks per half

    cn_stats_half<<<half, 256, 0, stream>>>(x, ws, 0);
    cn_norm_half <<<half, 256, 0, stream>>>(x, labels, rmean, rvar, wgt, bia, ws, out, 0);
    cn_stats_half<<<half, 256, 0, stream>>>(x, ws, 32);
    cn_norm_half <<<half, 256, 0, stream>>>(x, labels, rmean, rvar, wgt, bia, ws, out, 32);
}